// Round 6
// baseline (228.002 us; speedup 1.0000x reference)
//
#include <hip/hip_runtime.h>

typedef short short8 __attribute__((ext_vector_type(8)));
typedef float f32x4  __attribute__((ext_vector_type(4)));

constexpr int M_TOT  = 8 * 4096;   // 32768 pixels
constexpr int K_PROT = 1024;
constexpr int D_DIM  = 128;

// ws layout: xsq @0 (128 KB), psq @128K (4 KB), pfrag @132K (512 KB)
constexpr size_t WS_PSQ_OFF = (size_t)M_TOT * 4;
constexpr size_t WS_PF_OFF  = WS_PSQ_OFF + (size_t)K_PROT * 4;

constexpr int NORM_BLOCKS  = (M_TOT + K_PROT) / 8;  // 4224
constexpr int PFRAG_BLOCKS = 32768 / 256;           // 128

__device__ inline unsigned short bf16_hi(float f) {
  unsigned u = __builtin_bit_cast(unsigned, f);
  unsigned r = u + 0x7FFFu + ((u >> 16) & 1u);   // RNE
  return (unsigned short)(r >> 16);
}
__device__ inline float bf16_tof(unsigned short h) {
  return __builtin_bit_cast(float, (unsigned)h << 16);
}

// ---------------------------------------------------------------------------
// Fused prep: row norms (xsq, psq) + proto fragment pre-swizzle (pf).
// Blocks [0, 4224): norms; blocks [4224, 4352): pfrag.
__global__ __launch_bounds__(256) void prep_kernel(
    const float* __restrict__ x, const float* __restrict__ p,
    float* __restrict__ xsq, float* __restrict__ psq, short* __restrict__ pf) {
  const int bx  = blockIdx.x;
  const int tid = threadIdx.x;
  if (bx < NORM_BLOCKS) {
    int group = bx * 8 + (tid >> 5);
    int lane  = tid & 31;
    if (group >= M_TOT + K_PROT) return;
    const float* row = (group < M_TOT) ? (x + (size_t)group * D_DIM)
                                       : (p + (size_t)(group - M_TOT) * D_DIM);
    float4 v = reinterpret_cast<const float4*>(row)[lane];
    float s = v.x * v.x + v.y * v.y + v.z * v.z + v.w * v.w;
    #pragma unroll
    for (int off = 16; off > 0; off >>= 1) s += __shfl_down(s, off, 32);
    if (lane == 0) {
      if (group < M_TOT) xsq[group] = s;
      else psq[group - M_TOT] = s;
    }
  } else {
    int g    = (bx - NORM_BLOCKS) * 256 + tid;
    int lane = g & 63;
    int s    = (g >> 6) & 7;
    int ng   = g >> 9;
    int part = s >> 2, ks = s & 3;
    int proto = ng * 16 + (lane & 15);
    int k0    = ks * 32 + (lane >> 4) * 8;
    const float4* pr = (const float4*)(p + (size_t)proto * D_DIM + k0);
    float4 a = pr[0], b = pr[1];
    float e[8] = {a.x, a.y, a.z, a.w, b.x, b.y, b.z, b.w};
    short8 frag;
    #pragma unroll
    for (int j = 0; j < 8; ++j) {
      unsigned short h = bf16_hi(e[j]);
      if (part) h = bf16_hi(e[j] - bf16_tof(h));
      frag[j] = (short)h;
    }
    *(short8*)(pf + (size_t)g * 8) = frag;
  }
}

// ---------------------------------------------------------------------------
// R6: BARRIER-FREE chunk loop. Wave-private score staging (sw[w], 8 KB,
// XOR-swizzled, two mt-pair rounds/chunk) -> zero s_barrier between chunks;
// 8 waves/CU skew freely so loads/MFMA/stores overlap across waves. Next
// chunk's ks=0 pf frags + psq prefetched into regs BEFORE the drain stores
// (vmcnt FIFO: waits on these loads exclude the in-flight stores).
__global__ __launch_bounds__(256, 2) void proto_mfma(
    const float* __restrict__ x, const float* __restrict__ p,
    const short* __restrict__ pf, const float* __restrict__ xsq,
    const float* __restrict__ psq,
    float* __restrict__ matched, float* __restrict__ scores) {
  __shared__ short xlds[32 * 64 * 8];   // 32 KB: [part*16 + nt*4 + ks][lane][8]
  __shared__ float sw[4][2048];         // 32 KB: per-wave [64 rows][32 cols] swizzled
  __shared__ float svv[4][64];
  __shared__ int   sii[4][64];
  __shared__ int   fidx[64];

  const int tid  = threadIdx.x;
  const int w    = tid >> 6;
  const int l    = tid & 63;
  const int m0   = blockIdx.x * 64;
  const int csub = (l >> 4) << 2;       // 0,4,8,12

  // ---- stage x tile into LDS in B-fragment order, hi/lo split (once) ----
  #pragma unroll
  for (int i = 0; i < 8; ++i) {
    int piece = i * 256 + tid;          // 0..2047
    int s = piece >> 6;                 // 0..31
    int ks = s & 3, nt = (s >> 2) & 3, part = s >> 4;
    int pix = m0 + nt * 16 + (l & 15);
    int k0  = ks * 32 + (l >> 4) * 8;
    const float4* xr = (const float4*)(x + (size_t)pix * D_DIM + k0);
    float4 a = xr[0], b = xr[1];
    float e[8] = {a.x, a.y, a.z, a.w, b.x, b.y, b.z, b.w};
    short8 frag;
    #pragma unroll
    for (int j = 0; j < 8; ++j) {
      unsigned short h = bf16_hi(e[j]);
      if (part) h = bf16_hi(e[j] - bf16_tof(h));
      frag[j] = (short)h;
    }
    *(short8*)(xlds + (size_t)piece * 8) = frag;
  }
  __syncthreads();

  float xs[4];
  #pragma unroll
  for (int nt = 0; nt < 4; ++nt) xs[nt] = xsq[m0 + nt * 16 + (l & 15)];

  float best[4]; int bidx[4];
  #pragma unroll
  for (int nt = 0; nt < 4; ++nt) { best[nt] = -3.4e38f; bidx[nt] = 0; }

  // ---- prefetch chunk 0: ks=0 pf frags + psq ----
  short8 ppah[4], ppal[4];
  f32x4  cpsq[4];
  {
    const int pg0 = w * 4;
    #pragma unroll
    for (int mt = 0; mt < 4; ++mt) {
      ppah[mt] = *(const short8*)(pf + ((size_t)((pg0 + mt) * 8 + 0) * 64 + l) * 8);
      ppal[mt] = *(const short8*)(pf + ((size_t)((pg0 + mt) * 8 + 4) * 64 + l) * 8);
      cpsq[mt] = *(const f32x4*)(psq + w * 64 + mt * 16 + csub);
    }
  }

  for (int chunk = 0; chunk < 4; ++chunk) {
    f32x4 acc[4][4];
    #pragma unroll
    for (int mt = 0; mt < 4; ++mt)
      #pragma unroll
      for (int nt = 0; nt < 4; ++nt) acc[mt][nt] = (f32x4){0.f, 0.f, 0.f, 0.f};

    const int pgbase = chunk * 16 + w * 4;

    #pragma unroll
    for (int ks = 0; ks < 4; ++ks) {
      short8 pah[4], pal[4], bh[4], bl[4];
      if (ks == 0) {
        #pragma unroll
        for (int mt = 0; mt < 4; ++mt) { pah[mt] = ppah[mt]; pal[mt] = ppal[mt]; }
      } else {
        #pragma unroll
        for (int mt = 0; mt < 4; ++mt) {
          pah[mt] = *(const short8*)(pf + ((size_t)((pgbase + mt) * 8 + ks) * 64 + l) * 8);
          pal[mt] = *(const short8*)(pf + ((size_t)((pgbase + mt) * 8 + 4 + ks) * 64 + l) * 8);
        }
      }
      #pragma unroll
      for (int nt = 0; nt < 4; ++nt) {
        bh[nt] = *(const short8*)(xlds + (size_t)(((nt * 4 + ks) * 64) + l) * 8);
        bl[nt] = *(const short8*)(xlds + (size_t)(((16 + nt * 4 + ks) * 64) + l) * 8);
      }
      #pragma unroll
      for (int mt = 0; mt < 4; ++mt)
        #pragma unroll
        for (int nt = 0; nt < 4; ++nt)
          acc[mt][nt] = __builtin_amdgcn_mfma_f32_16x16x32_bf16(pah[mt], bh[nt], acc[mt][nt], 0, 0, 0);
      #pragma unroll
      for (int mt = 0; mt < 4; ++mt)
        #pragma unroll
        for (int nt = 0; nt < 4; ++nt)
          acc[mt][nt] = __builtin_amdgcn_mfma_f32_16x16x32_bf16(pah[mt], bl[nt], acc[mt][nt], 0, 0, 0);
      #pragma unroll
      for (int mt = 0; mt < 4; ++mt)
        #pragma unroll
        for (int nt = 0; nt < 4; ++nt)
          acc[mt][nt] = __builtin_amdgcn_mfma_f32_16x16x32_bf16(pal[mt], bh[nt], acc[mt][nt], 0, 0, 0);
    }

    // ---- epilogue: finalize scores in acc + running per-pixel argmax ----
    #pragma unroll
    for (int mt = 0; mt < 4; ++mt) {
      int pbase = chunk * 256 + w * 64 + mt * 16 + csub;
      float psa[4] = {cpsq[mt][0], cpsq[mt][1], cpsq[mt][2], cpsq[mt][3]};
      #pragma unroll
      for (int nt = 0; nt < 4; ++nt) {
        f32x4 o;
        {
          #pragma clang fp contract(off)
          #pragma unroll
          for (int r = 0; r < 4; ++r) {
            float t = (xs[nt] + psa[r]) - 2.0f * acc[mt][nt][r];
            o[r] = -t;
            if (o[r] > best[nt]) { best[nt] = o[r]; bidx[nt] = pbase + r; }
          }
        }
        acc[mt][nt] = o;
      }
    }

    // ---- prefetch next chunk (ks=0 + psq) BEFORE issuing drain stores ----
    if (chunk < 3) {
      const int npg = pgbase + 16;
      #pragma unroll
      for (int mt = 0; mt < 4; ++mt) {
        ppah[mt] = *(const short8*)(pf + ((size_t)((npg + mt) * 8 + 0) * 64 + l) * 8);
        ppal[mt] = *(const short8*)(pf + ((size_t)((npg + mt) * 8 + 4) * 64 + l) * 8);
        cpsq[mt] = *(const f32x4*)(psq + (chunk + 1) * 256 + w * 64 + mt * 16 + csub);
      }
    }

    // ---- two wave-private stage+drain rounds (NO barriers) ----
    #pragma unroll
    for (int mp = 0; mp < 2; ++mp) {
      #pragma unroll
      for (int mt2 = 0; mt2 < 2; ++mt2) {
        int mt = mp * 2 + mt2;
        #pragma unroll
        for (int nt = 0; nt < 4; ++nt) {
          int row = nt * 16 + (l & 15);
          int col = mt2 * 16 + csub;
          int idx = (row << 5) + (col ^ ((row & 7) << 2));
          *(f32x4*)&sw[w][idx] = acc[mt][nt];
        }
      }
      const int drow = l >> 3;          // 0..7
      const int dcol = (l & 7) << 2;    // 0..28
      #pragma unroll
      for (int ps = 0; ps < 8; ++ps) {
        int row = (ps << 3) + drow;
        int idx = (row << 5) + (dcol ^ (drow << 2));
        f32x4 v = *(const f32x4*)&sw[w][idx];
        *((f32x4*)(scores + (size_t)(m0 + row) * K_PROT + chunk * 256 + (w << 6) + (mp << 5)) + (l & 7)) = v;
      }
    }
  }

  // ---- argmax reduce: butterfly over quads, then LDS over waves ----
  #pragma unroll
  for (int nt = 0; nt < 4; ++nt) {
    #pragma unroll
    for (int m = 16; m <= 32; m <<= 1) {
      float ov = __shfl_xor(best[nt], m);
      int   oi = __shfl_xor(bidx[nt], m);
      if (ov > best[nt] || (ov == best[nt] && oi < bidx[nt])) {
        best[nt] = ov; bidx[nt] = oi;
      }
    }
  }
  if (l < 16) {
    #pragma unroll
    for (int nt = 0; nt < 4; ++nt) {
      svv[w][nt * 16 + l] = best[nt];
      sii[w][nt * 16 + l] = bidx[nt];
    }
  }
  __syncthreads();
  if (tid < 64) {
    float v = svv[0][tid]; int bi = sii[0][tid];
    #pragma unroll
    for (int e = 1; e < 4; ++e) {
      float vv = svv[e][tid]; int ii = sii[e][tid];
      if (vv > v || (vv == v && ii < bi)) { v = vv; bi = ii; }
    }
    fidx[tid] = bi;
  }
  __syncthreads();

  // ---- gather matched = original fp32 prototypes[argmax] ----
  for (int q = tid; q < 64 * 32; q += 256) {
    int pix = q >> 5, f4 = q & 31;
    float4 v = ((const float4*)(p + (size_t)fidx[pix] * D_DIM))[f4];
    *((f32x4*)(matched + (size_t)(m0 + pix) * D_DIM) + f4) = *(f32x4*)&v;
  }
}

// ---------------------------------------------------------------------------
extern "C" void kernel_launch(void* const* d_in, const int* in_sizes, int n_in,
                              void* d_out, int out_size, void* d_ws, size_t ws_size,
                              hipStream_t stream) {
  const float* x = (const float*)d_in[0];   // [B,N,D] fp32
  const float* p = (const float*)d_in[1];   // [K,D]   fp32

  float* matched = (float*)d_out;                            // [B,N,D]
  float* scores  = (float*)d_out + (size_t)M_TOT * D_DIM;    // [B,N,K]

  float* xsq = (float*)d_ws;
  float* psq = (float*)((char*)d_ws + WS_PSQ_OFF);
  short* pf  = (short*)((char*)d_ws + WS_PF_OFF);

  prep_kernel<<<NORM_BLOCKS + PFRAG_BLOCKS, 256, 0, stream>>>(x, p, xsq, psq, pf);
  proto_mfma<<<M_TOT / 64, 256, 0, stream>>>(x, p, pf, xsq, psq, matched, scores);
}

// Round 7
// 187.671 us; speedup vs baseline: 1.2149x; 1.2149x over previous
//
#include <hip/hip_runtime.h>

typedef short short8 __attribute__((ext_vector_type(8)));
typedef float f32x4  __attribute__((ext_vector_type(4)));

constexpr int M_TOT  = 8 * 4096;   // 32768 pixels
constexpr int K_PROT = 1024;
constexpr int D_DIM  = 128;

// ws layout: xsq @0 (128 KB), psq @128K (4 KB), pfrag @132K (512 KB)
constexpr size_t WS_PSQ_OFF = (size_t)M_TOT * 4;
constexpr size_t WS_PF_OFF  = WS_PSQ_OFF + (size_t)K_PROT * 4;

constexpr int NORM_BLOCKS  = (M_TOT + K_PROT) / 8;  // 4224
constexpr int PFRAG_BLOCKS = 32768 / 256;           // 128

__device__ inline unsigned short bf16_hi(float f) {
  unsigned u = __builtin_bit_cast(unsigned, f);
  unsigned r = u + 0x7FFFu + ((u >> 16) & 1u);   // RNE
  return (unsigned short)(r >> 16);
}
__device__ inline float bf16_tof(unsigned short h) {
  return __builtin_bit_cast(float, (unsigned)h << 16);
}

// LDS-only barrier: ds ops complete (lgkmcnt), but do NOT drain in-flight
// global stores (vmcnt) like __syncthreads() would.
__device__ inline void barrier_lds() {
  asm volatile("s_waitcnt lgkmcnt(0)\n\ts_barrier" ::: "memory");
}

// ---------------------------------------------------------------------------
// Fused prep: row norms (xsq, psq) + proto fragment pre-swizzle (pf).
// Blocks [0, 4224): norms; blocks [4224, 4352): pfrag.
__global__ __launch_bounds__(256) void prep_kernel(
    const float* __restrict__ x, const float* __restrict__ p,
    float* __restrict__ xsq, float* __restrict__ psq, short* __restrict__ pf) {
  const int bx  = blockIdx.x;
  const int tid = threadIdx.x;
  if (bx < NORM_BLOCKS) {
    int group = bx * 8 + (tid >> 5);
    int lane  = tid & 31;
    if (group >= M_TOT + K_PROT) return;
    const float* row = (group < M_TOT) ? (x + (size_t)group * D_DIM)
                                       : (p + (size_t)(group - M_TOT) * D_DIM);
    float4 v = reinterpret_cast<const float4*>(row)[lane];
    float s = v.x * v.x + v.y * v.y + v.z * v.z + v.w * v.w;
    #pragma unroll
    for (int off = 16; off > 0; off >>= 1) s += __shfl_down(s, off, 32);
    if (lane == 0) {
      if (group < M_TOT) xsq[group] = s;
      else psq[group - M_TOT] = s;
    }
  } else {
    // pf: g -> ng=g>>9 (16-proto group), slot=(g>>6)&7 (part*4+ks), lane=g&63.
    int g    = (bx - NORM_BLOCKS) * 256 + tid;
    int lane = g & 63;
    int s    = (g >> 6) & 7;
    int ng   = g >> 9;
    int part = s >> 2, ks = s & 3;
    int proto = ng * 16 + (lane & 15);
    int k0    = ks * 32 + (lane >> 4) * 8;
    const float4* pr = (const float4*)(p + (size_t)proto * D_DIM + k0);
    float4 a = pr[0], b = pr[1];
    float e[8] = {a.x, a.y, a.z, a.w, b.x, b.y, b.z, b.w};
    short8 frag;
    #pragma unroll
    for (int j = 0; j < 8; ++j) {
      unsigned short h = bf16_hi(e[j]);
      if (part) h = bf16_hi(e[j] - bf16_tof(h));
      frag[j] = (short)h;
    }
    *(short8*)(pf + (size_t)g * 8) = frag;
  }
}

// ---------------------------------------------------------------------------
// Main: A=protos (pf via L2, LOCKSTEP across waves/blocks -> L2-resident),
// B=pixels (LDS). Block = 64 pix, 4 waves; wave w covers protos
// [chunk*256 + w*64, +64) over 4 chunks.
// C/D: col(lane&15)=pixel, row=(lane>>4)*4+reg = 4 consecutive protos.
// R7 = R5 lockstep structure (barriers restored: they ARE the pf L2 strategy;
// R6's barrier-free skew caused 87 MB of pf HBM re-fetch + dirty-partial-line
// write amplification) + smaller staging buffer sbuf[64][68] (one wave stages
// per 64-col round) -> LDS 52.5 KB -> 3 blocks/CU (12 waves, +50% latency
// hiding vs R5's 2) to attack the measured latency-bound signature.
__global__ __launch_bounds__(256, 3) void proto_mfma(
    const float* __restrict__ x, const float* __restrict__ p,
    const short* __restrict__ pf, const float* __restrict__ xsq,
    const float* __restrict__ psq,
    float* __restrict__ matched, float* __restrict__ scores) {
  __shared__ short xlds[32 * 64 * 8];   // 32 KB: [part*16 + nt*4 + ks][lane][8]
  __shared__ float sbuf[64][68];        // 17.4 KB score staging (pad 4 dwords)
  __shared__ float sv[4][64];
  __shared__ int   si[4][64];
  __shared__ int   fidx[64];

  const int tid  = threadIdx.x;
  const int w    = tid >> 6;
  const int l    = tid & 63;
  const int m0   = blockIdx.x * 64;
  const int csub = (l >> 4) << 2;       // 0,4,8,12

  // ---- stage x tile into LDS in B-fragment order, hi/lo split (once) ----
  #pragma unroll
  for (int i = 0; i < 8; ++i) {
    int piece = i * 256 + tid;          // 0..2047
    int s = piece >> 6;                 // 0..31
    int ks = s & 3, nt = (s >> 2) & 3, part = s >> 4;
    int pix = m0 + nt * 16 + (l & 15);
    int k0  = ks * 32 + (l >> 4) * 8;
    const float4* xr = (const float4*)(x + (size_t)pix * D_DIM + k0);
    float4 a = xr[0], b = xr[1];
    float e[8] = {a.x, a.y, a.z, a.w, b.x, b.y, b.z, b.w};
    short8 frag;
    #pragma unroll
    for (int j = 0; j < 8; ++j) {
      unsigned short h = bf16_hi(e[j]);
      if (part) h = bf16_hi(e[j] - bf16_tof(h));
      frag[j] = (short)h;
    }
    *(short8*)(xlds + (size_t)piece * 8) = frag;
  }
  __syncthreads();

  float xs[4];
  #pragma unroll
  for (int nt = 0; nt < 4; ++nt) xs[nt] = xsq[m0 + nt * 16 + (l & 15)];

  float best[4]; int bidx[4];
  #pragma unroll
  for (int nt = 0; nt < 4; ++nt) { best[nt] = -3.4e38f; bidx[nt] = 0; }

  for (int chunk = 0; chunk < 4; ++chunk) {
    f32x4 acc[4][4];
    #pragma unroll
    for (int mt = 0; mt < 4; ++mt)
      #pragma unroll
      for (int nt = 0; nt < 4; ++nt) acc[mt][nt] = (f32x4){0.f, 0.f, 0.f, 0.f};

    const int pgbase = chunk * 16 + w * 4;

    #pragma unroll
    for (int ks = 0; ks < 4; ++ks) {
      short8 pah[4], pal[4], bh[4], bl[4];
      #pragma unroll
      for (int mt = 0; mt < 4; ++mt) {
        pah[mt] = *(const short8*)(pf + ((size_t)((pgbase + mt) * 8 + ks) * 64 + l) * 8);
        pal[mt] = *(const short8*)(pf + ((size_t)((pgbase + mt) * 8 + 4 + ks) * 64 + l) * 8);
      }
      #pragma unroll
      for (int nt = 0; nt < 4; ++nt) {
        bh[nt] = *(const short8*)(xlds + (size_t)(((nt * 4 + ks) * 64) + l) * 8);
        bl[nt] = *(const short8*)(xlds + (size_t)(((16 + nt * 4 + ks) * 64) + l) * 8);
      }
      #pragma unroll
      for (int mt = 0; mt < 4; ++mt)
        #pragma unroll
        for (int nt = 0; nt < 4; ++nt)
          acc[mt][nt] = __builtin_amdgcn_mfma_f32_16x16x32_bf16(pah[mt], bh[nt], acc[mt][nt], 0, 0, 0);
      #pragma unroll
      for (int mt = 0; mt < 4; ++mt)
        #pragma unroll
        for (int nt = 0; nt < 4; ++nt)
          acc[mt][nt] = __builtin_amdgcn_mfma_f32_16x16x32_bf16(pah[mt], bl[nt], acc[mt][nt], 0, 0, 0);
      #pragma unroll
      for (int mt = 0; mt < 4; ++mt)
        #pragma unroll
        for (int nt = 0; nt < 4; ++nt)
          acc[mt][nt] = __builtin_amdgcn_mfma_f32_16x16x32_bf16(pal[mt], bh[nt], acc[mt][nt], 0, 0, 0);
    }

    // ---- transform acc in place to final score values + running argmax ----
    #pragma unroll
    for (int mt = 0; mt < 4; ++mt) {
      int pbase = chunk * 256 + w * 64 + mt * 16 + csub;
      float psa[4];
      *(float4*)psa = *(const float4*)(psq + pbase);
      #pragma unroll
      for (int nt = 0; nt < 4; ++nt) {
        f32x4 o;
        {
          #pragma clang fp contract(off)
          #pragma unroll
          for (int r = 0; r < 4; ++r) {
            float t = (xs[nt] + psa[r]) - 2.0f * acc[mt][nt][r];
            o[r] = -t;
            if (o[r] > best[nt]) { best[nt] = o[r]; bidx[nt] = pbase + r; }
          }
        }
        acc[mt][nt] = o;   // acc now holds final scores
      }
    }

    // ---- 4 staging+drain rounds: round r drains wave r's 64 proto-cols;
    //      drain instr = 256 B contiguous run per row (full L2 lines) ----
    #pragma unroll
    for (int r = 0; r < 4; ++r) {
      if (w == r) {
        #pragma unroll
        for (int mt = 0; mt < 4; ++mt)
          #pragma unroll
          for (int nt = 0; nt < 4; ++nt)
            *(f32x4*)&sbuf[nt * 16 + (l & 15)][mt * 16 + csub] = acc[mt][nt];
      }
      barrier_lds();
      #pragma unroll
      for (int ps = 0; ps < 4; ++ps) {
        int idx = ps * 256 + tid;       // 0..1023
        int row = idx >> 4;             // 0..63 (16 f32x4 per row)
        int c4  = idx & 15;             // 0..15
        f32x4 v = *(const f32x4*)&sbuf[row][c4 * 4];
        *((f32x4*)(scores + (size_t)(m0 + row) * K_PROT + chunk * 256 + r * 64) + c4) = v;
      }
      barrier_lds();   // readers done before next round's writer overwrites sbuf
    }
  }

  // ---- argmax reduce: butterfly over quads, then LDS over waves ----
  #pragma unroll
  for (int nt = 0; nt < 4; ++nt) {
    #pragma unroll
    for (int m = 16; m <= 32; m <<= 1) {
      float ov = __shfl_xor(best[nt], m);
      int   oi = __shfl_xor(bidx[nt], m);
      if (ov > best[nt] || (ov == best[nt] && oi < bidx[nt])) {
        best[nt] = ov; bidx[nt] = oi;
      }
    }
  }
  if (l < 16) {
    #pragma unroll
    for (int nt = 0; nt < 4; ++nt) {
      sv[w][nt * 16 + l] = best[nt];
      si[w][nt * 16 + l] = bidx[nt];
    }
  }
  __syncthreads();
  if (tid < 64) {
    float v = sv[0][tid]; int bi = si[0][tid];
    #pragma unroll
    for (int e = 1; e < 4; ++e) {
      float vv = sv[e][tid]; int ii = si[e][tid];
      if (vv > v || (vv == v && ii < bi)) { v = vv; bi = ii; }
    }
    fidx[tid] = bi;
  }
  __syncthreads();

  // ---- gather matched = original fp32 prototypes[argmax] ----
  for (int q = tid; q < 64 * 32; q += 256) {
    int pix = q >> 5, f4 = q & 31;
    float4 v = ((const float4*)(p + (size_t)fidx[pix] * D_DIM))[f4];
    *((f32x4*)(matched + (size_t)(m0 + pix) * D_DIM) + f4) = *(f32x4*)&v;
  }
}

// ---------------------------------------------------------------------------
extern "C" void kernel_launch(void* const* d_in, const int* in_sizes, int n_in,
                              void* d_out, int out_size, void* d_ws, size_t ws_size,
                              hipStream_t stream) {
  const float* x = (const float*)d_in[0];   // [B,N,D] fp32
  const float* p = (const float*)d_in[1];   // [K,D]   fp32

  float* matched = (float*)d_out;                            // [B,N,D]
  float* scores  = (float*)d_out + (size_t)M_TOT * D_DIM;    // [B,N,K]

  float* xsq = (float*)d_ws;
  float* psq = (float*)((char*)d_ws + WS_PSQ_OFF);
  short* pf  = (short*)((char*)d_ws + WS_PF_OFF);

  prep_kernel<<<NORM_BLOCKS + PFRAG_BLOCKS, 256, 0, stream>>>(x, p, xsq, psq, pf);
  proto_mfma<<<M_TOT / 64, 256, 0, stream>>>(x, p, pf, xsq, psq, matched, scores);
}

// Round 8
// 170.956 us; speedup vs baseline: 1.3337x; 1.0978x over previous
//
#include <hip/hip_runtime.h>

typedef short short8 __attribute__((ext_vector_type(8)));
typedef float f32x4  __attribute__((ext_vector_type(4)));

constexpr int M_TOT  = 8 * 4096;   // 32768 pixels
constexpr int K_PROT = 1024;
constexpr int D_DIM  = 128;

// ws layout: xsq @0 (128 KB), psq @128K (4 KB), pfrag @132K (256 KB)
constexpr size_t WS_PSQ_OFF = (size_t)M_TOT * 4;
constexpr size_t WS_PF_OFF  = WS_PSQ_OFF + (size_t)K_PROT * 4;

constexpr int NORM_BLOCKS  = (M_TOT + K_PROT) / 8;  // 4224
constexpr int PFRAG_BLOCKS = 16384 / 256;           // 64 (single-part frags)

__device__ inline unsigned short bf16_rne(float f) {
  unsigned u = __builtin_bit_cast(unsigned, f);
  unsigned r = u + 0x7FFFu + ((u >> 16) & 1u);   // RNE
  return (unsigned short)(r >> 16);
}

// LDS-only barrier: ds ops complete (lgkmcnt), but do NOT drain in-flight
// global stores (vmcnt) like __syncthreads() would.
__device__ inline void barrier_lds() {
  asm volatile("s_waitcnt lgkmcnt(0)\n\ts_barrier" ::: "memory");
}

// ---------------------------------------------------------------------------
// Fused prep: row norms (xsq, psq) + proto fragment pre-swizzle (pf).
// Blocks [0, 4224): norms; blocks [4224, 4288): pfrag.
// pf (single bf16, no hi/lo split): g in [0,16384): ng=g>>8 (16-proto group),
// ks=(g>>6)&3, lane=g&63. proto = ng*16 + (lane&15), k = ks*32 + (lane>>4)*8+j.
__global__ __launch_bounds__(256) void prep_kernel(
    const float* __restrict__ x, const float* __restrict__ p,
    float* __restrict__ xsq, float* __restrict__ psq, short* __restrict__ pf) {
  const int bx  = blockIdx.x;
  const int tid = threadIdx.x;
  if (bx < NORM_BLOCKS) {
    int group = bx * 8 + (tid >> 5);
    int lane  = tid & 31;
    if (group >= M_TOT + K_PROT) return;
    const float* row = (group < M_TOT) ? (x + (size_t)group * D_DIM)
                                       : (p + (size_t)(group - M_TOT) * D_DIM);
    float4 v = reinterpret_cast<const float4*>(row)[lane];
    float s = v.x * v.x + v.y * v.y + v.z * v.z + v.w * v.w;
    #pragma unroll
    for (int off = 16; off > 0; off >>= 1) s += __shfl_down(s, off, 32);
    if (lane == 0) {
      if (group < M_TOT) xsq[group] = s;
      else psq[group - M_TOT] = s;
    }
  } else {
    int g    = (bx - NORM_BLOCKS) * 256 + tid;   // 0..16383
    int lane = g & 63;
    int ks   = (g >> 6) & 3;
    int ng   = g >> 8;
    int proto = ng * 16 + (lane & 15);
    int k0    = ks * 32 + (lane >> 4) * 8;
    const float4* pr = (const float4*)(p + (size_t)proto * D_DIM + k0);
    float4 a = pr[0], b = pr[1];
    float e[8] = {a.x, a.y, a.z, a.w, b.x, b.y, b.z, b.w};
    short8 frag;
    #pragma unroll
    for (int j = 0; j < 8; ++j) frag[j] = (short)bf16_rne(e[j]);
    *(short8*)(pf + (size_t)g * 8) = frag;
  }
}

// ---------------------------------------------------------------------------
// Main: A=protos (pf via L2, lockstep across waves/blocks -> L2-resident),
// B=pixels (LDS). Block = 64 pix, 4 waves; wave w covers protos
// [chunk*256 + w*64, +64) over 4 chunks.
// C/D: col(lane&15)=pixel, row=(lane>>4)*4+reg = 4 consecutive protos.
// R8 = R5 lockstep structure EXACTLY (2/CU, sbuf[64][132], two half-rounds,
// plain stores) but SINGLE-PASS bf16 (no hi/lo split): rounding error std
// ~0.004 on scores vs tolerance 1.0. MFMAs 768->256/wave, pf loads and
// stage-conversion VALU halve -> shortens the latency-bound serial chain.
__global__ __launch_bounds__(256, 2) void proto_mfma(
    const float* __restrict__ x, const float* __restrict__ p,
    const short* __restrict__ pf, const float* __restrict__ xsq,
    const float* __restrict__ psq,
    float* __restrict__ matched, float* __restrict__ scores) {
  __shared__ short xlds[16 * 64 * 8];   // 16 KB: [nt*4 + ks][lane][8]
  __shared__ float sbuf[64][132];       // 33.8 KB score staging (pad 4 -> 2-way banks)
  __shared__ float sv[4][64];
  __shared__ int   si[4][64];
  __shared__ int   fidx[64];

  const int tid  = threadIdx.x;
  const int w    = tid >> 6;
  const int l    = tid & 63;
  const int m0   = blockIdx.x * 64;
  const int csub = (l >> 4) << 2;       // 0,4,8,12

  // ---- stage x tile into LDS in B-fragment order, single bf16 (once) ----
  #pragma unroll
  for (int i = 0; i < 4; ++i) {
    int piece = i * 256 + tid;          // 0..1023
    int s = piece >> 6;                 // 0..15
    int ks = s & 3, nt = s >> 2;
    int pix = m0 + nt * 16 + (l & 15);
    int k0  = ks * 32 + (l >> 4) * 8;
    const float4* xr = (const float4*)(x + (size_t)pix * D_DIM + k0);
    float4 a = xr[0], b = xr[1];
    float e[8] = {a.x, a.y, a.z, a.w, b.x, b.y, b.z, b.w};
    short8 frag;
    #pragma unroll
    for (int j = 0; j < 8; ++j) frag[j] = (short)bf16_rne(e[j]);
    *(short8*)(xlds + (size_t)piece * 8) = frag;
  }
  __syncthreads();

  float xs[4];
  #pragma unroll
  for (int nt = 0; nt < 4; ++nt) xs[nt] = xsq[m0 + nt * 16 + (l & 15)];

  float best[4]; int bidx[4];
  #pragma unroll
  for (int nt = 0; nt < 4; ++nt) { best[nt] = -3.4e38f; bidx[nt] = 0; }

  for (int chunk = 0; chunk < 4; ++chunk) {
    f32x4 acc[4][4];
    #pragma unroll
    for (int mt = 0; mt < 4; ++mt)
      #pragma unroll
      for (int nt = 0; nt < 4; ++nt) acc[mt][nt] = (f32x4){0.f, 0.f, 0.f, 0.f};

    const int pgbase = chunk * 16 + w * 4;

    #pragma unroll
    for (int ks = 0; ks < 4; ++ks) {
      short8 pah[4], bh[4];
      #pragma unroll
      for (int mt = 0; mt < 4; ++mt)
        pah[mt] = *(const short8*)(pf + ((size_t)((pgbase + mt) * 4 + ks) * 64 + l) * 8);
      #pragma unroll
      for (int nt = 0; nt < 4; ++nt)
        bh[nt] = *(const short8*)(xlds + (size_t)(((nt * 4 + ks) * 64) + l) * 8);
      #pragma unroll
      for (int mt = 0; mt < 4; ++mt)
        #pragma unroll
        for (int nt = 0; nt < 4; ++nt)
          acc[mt][nt] = __builtin_amdgcn_mfma_f32_16x16x32_bf16(pah[mt], bh[nt], acc[mt][nt], 0, 0, 0);
    }

    // ---- transform acc in place to final score values + running argmax ----
    #pragma unroll
    for (int mt = 0; mt < 4; ++mt) {
      int pbase = chunk * 256 + w * 64 + mt * 16 + csub;
      float psa[4];
      *(float4*)psa = *(const float4*)(psq + pbase);
      #pragma unroll
      for (int nt = 0; nt < 4; ++nt) {
        f32x4 o;
        {
          #pragma clang fp contract(off)
          #pragma unroll
          for (int r = 0; r < 4; ++r) {
            float t = (xs[nt] + psa[r]) - 2.0f * acc[mt][nt][r];
            o[r] = -t;
            if (o[r] > best[nt]) { best[nt] = o[r]; bidx[nt] = pbase + r; }
          }
        }
        acc[mt][nt] = o;   // acc now holds final scores
      }
    }

    // ---- two staging+store rounds: waves {2h,2h+1} stage cols [h*128,+128) ----
    #pragma unroll
    for (int h = 0; h < 2; ++h) {
      if ((w >> 1) == h) {
        const int colbase = (w & 1) * 64 + csub;
        #pragma unroll
        for (int mt = 0; mt < 4; ++mt)
          #pragma unroll
          for (int nt = 0; nt < 4; ++nt)
            *(f32x4*)&sbuf[nt * 16 + (l & 15)][colbase + mt * 16] = acc[mt][nt];
      }
      barrier_lds();
      const int gbase = chunk * 256 + h * 128;
      #pragma unroll
      for (int ps = 0; ps < 8; ++ps) {
        int idx = ps * 256 + tid;
        int row = idx >> 5;          // 0..63 (8 rows per pass)
        int f4  = idx & 31;          // 0..31 (128 cols / 4)
        f32x4 v = *(const f32x4*)&sbuf[row][f4 * 4];
        *((f32x4*)(scores + (size_t)(m0 + row) * K_PROT + gbase + f4 * 4)) = v;
      }
      barrier_lds();   // readers done before next round's writers overwrite sbuf
    }
  }

  // ---- argmax reduce: butterfly over quads, then LDS over waves ----
  #pragma unroll
  for (int nt = 0; nt < 4; ++nt) {
    #pragma unroll
    for (int m = 16; m <= 32; m <<= 1) {
      float ov = __shfl_xor(best[nt], m);
      int   oi = __shfl_xor(bidx[nt], m);
      if (ov > best[nt] || (ov == best[nt] && oi < bidx[nt])) {
        best[nt] = ov; bidx[nt] = oi;
      }
    }
  }
  if (l < 16) {
    #pragma unroll
    for (int nt = 0; nt < 4; ++nt) {
      sv[w][nt * 16 + l] = best[nt];
      si[w][nt * 16 + l] = bidx[nt];
    }
  }
  __syncthreads();
  if (tid < 64) {
    float v = sv[0][tid]; int bi = si[0][tid];
    #pragma unroll
    for (int e = 1; e < 4; ++e) {
      float vv = sv[e][tid]; int ii = si[e][tid];
      if (vv > v || (vv == v && ii < bi)) { v = vv; bi = ii; }
    }
    fidx[tid] = bi;
  }
  __syncthreads();

  // ---- gather matched = original fp32 prototypes[argmax] ----
  for (int q = tid; q < 64 * 32; q += 256) {
    int pix = q >> 5, f4 = q & 31;
    float4 v = ((const float4*)(p + (size_t)fidx[pix] * D_DIM))[f4];
    *((f32x4*)(matched + (size_t)(m0 + pix) * D_DIM) + f4) = *(f32x4*)&v;
  }
}

// ---------------------------------------------------------------------------
extern "C" void kernel_launch(void* const* d_in, const int* in_sizes, int n_in,
                              void* d_out, int out_size, void* d_ws, size_t ws_size,
                              hipStream_t stream) {
  const float* x = (const float*)d_in[0];   // [B,N,D] fp32
  const float* p = (const float*)d_in[1];   // [K,D]   fp32

  float* matched = (float*)d_out;                            // [B,N,D]
  float* scores  = (float*)d_out + (size_t)M_TOT * D_DIM;    // [B,N,K]

  float* xsq = (float*)d_ws;
  float* psq = (float*)((char*)d_ws + WS_PSQ_OFF);
  short* pf  = (short*)((char*)d_ws + WS_PF_OFF);

  prep_kernel<<<NORM_BLOCKS + PFRAG_BLOCKS, 256, 0, stream>>>(x, p, xsq, psq, pf);
  proto_mfma<<<M_TOT / 64, 256, 0, stream>>>(x, p, pf, xsq, psq, matched, scores);
}